// Round 1
// baseline (670.940 us; speedup 1.0000x reference)
//
#include <hip/hip_runtime.h>
#include <cstdint>
#include <cstddef>

typedef _Float16 f16;
typedef _Float16 f16x4 __attribute__((ext_vector_type(4)));
typedef _Float16 f16x8 __attribute__((ext_vector_type(8)));
typedef float f32x4 __attribute__((ext_vector_type(4)));

// ---------------------------------------------------------------------------
// async global->LDS, 16B per lane. LDS dest is WAVE-UNIFORM base; HW writes
// lane i at base + i*16 (m97/m104 semantics).
// ---------------------------------------------------------------------------
__device__ __forceinline__ void gl2lds16(const void* g, void* l) {
  __builtin_amdgcn_global_load_lds(
      (const __attribute__((address_space(1))) void*)(uintptr_t)g,
      (__attribute__((address_space(3))) void*)(uintptr_t)l,
      16, 0, 0);
}

// ---------------------------------------------------------------------------
// Weight prep via LDS-bounce transpose. Tile 32 o x 32 i per block.
// Wt[o][i*9+0] = sb[i,o]; Wt[o][i*9+1+g] = coef[i,o,g]*ss[i,o].
// ---------------------------------------------------------------------------
__global__ __launch_bounds__(256) void kan_prep2(
    const float* __restrict__ coef, const float* __restrict__ sb,
    const float* __restrict__ ss, f16* __restrict__ Wt,
    int out, int K9)
{
  __shared__ float s_sb[32][32];   // [i][o]
  __shared__ float s_ss[32][32];
  __shared__ f16 s_w[32][288];     // [o][i*9+t]
  const int t  = threadIdx.x;
  const int o0 = blockIdx.x * 32, i0 = blockIdx.y * 32;

  {
    int il = t >> 3, oc = (t & 7) * 4;
    float4 vb = *(const float4*)(sb + (size_t)(i0 + il) * out + o0 + oc);
    float4 vs = *(const float4*)(ss + (size_t)(i0 + il) * out + o0 + oc);
    s_sb[il][oc + 0] = vb.x; s_sb[il][oc + 1] = vb.y;
    s_sb[il][oc + 2] = vb.z; s_sb[il][oc + 3] = vb.w;
    s_ss[il][oc + 0] = vs.x; s_ss[il][oc + 1] = vs.y;
    s_ss[il][oc + 2] = vs.z; s_ss[il][oc + 3] = vs.w;
  }
  __syncthreads();

#pragma unroll
  for (int j = 0; j < 8; ++j) {
    int f  = j * 256 + t;
    int il = f >> 6, c = f & 63;
    int ol = c >> 1, gh = (c & 1) * 4;
    float4 v = *(const float4*)(coef + ((size_t)(i0 + il) * out + (o0 + ol)) * 8 + gh);
    float ssv = s_ss[il][ol];
    f16* dst = &s_w[ol][il * 9 + 1 + gh];
    dst[0] = (f16)(v.x * ssv); dst[1] = (f16)(v.y * ssv);
    dst[2] = (f16)(v.z * ssv); dst[3] = (f16)(v.w * ssv);
  }
#pragma unroll
  for (int j = 0; j < 4; ++j) {
    int e = j * 256 + t; int il = e >> 5, ol = e & 31;
    s_w[ol][il * 9] = (f16)s_sb[il][ol];
  }
  __syncthreads();

  {
    int o = t >> 3, part = t & 7;
    f16* dst = Wt + (size_t)(o0 + o) * K9 + (size_t)i0 * 9 + part * 36;
    const f16* src = &s_w[o][part * 36];
#pragma unroll
    for (int q = 0; q < 9; ++q)
      *(f16x4*)(dst + q * 4) = *(const f16x4*)(src + q * 4);
  }
}

// ---------------------------------------------------------------------------
// Features: per x -> [silu(x), B3_0(x)..B3_7(x)] fp16, row-major F[b][i*9+t].
// Uniform pykan grid hardcoded: t_j = (j-3)*0.4 - 1.
// ---------------------------------------------------------------------------
__global__ __launch_bounds__(256) void kan_feat(
    const float* __restrict__ X, f16* __restrict__ F,
    int shift, int K9, int iBase)
{
  int idx = blockIdx.x * 256 + threadIdx.x;
  int b  = idx >> shift;
  int ii = idx & ((1 << shift) - 1);
  float x = X[idx];

  float sig  = 1.0f / (1.0f + __expf(-x));
  float silu = x * sig;

  float t[12];
#pragma unroll
  for (int j = 0; j < 12; ++j) t[j] = (float)(j - 3) * 0.4f - 1.0f;
  float b0[11];
#pragma unroll
  for (int j = 0; j < 11; ++j)
    b0[j] = (x >= t[j] && x < t[j + 1]) ? 1.0f : 0.0f;
  float b1[10];
#pragma unroll
  for (int j = 0; j < 10; ++j)
    b1[j] = (x - t[j]) * 2.5f * b0[j] + (t[j + 2] - x) * 2.5f * b0[j + 1];
  float b2[9];
#pragma unroll
  for (int j = 0; j < 9; ++j)
    b2[j] = (x - t[j]) * 1.25f * b1[j] + (t[j + 3] - x) * 1.25f * b1[j + 1];
  float b3[8];
#pragma unroll
  for (int j = 0; j < 8; ++j)
    b3[j] = (x - t[j]) * (1.0f / 1.2f) * b2[j] +
            (t[j + 4] - x) * (1.0f / 1.2f) * b2[j + 1];

  f16* o = F + (size_t)b * K9 + (size_t)(iBase + ii) * 9;
  o[0] = (f16)silu;
#pragma unroll
  for (int g = 0; g < 8; ++g) o[1 + g] = (f16)b3[g];
}

// ---------------------------------------------------------------------------
// GEMM: C[M,N] += A[M,K] * Bt[N,K]^T, fp16 in / fp32 out.
// Block 256x256, BK=32, 8 waves (2Mx4N), wave tile 128x64, acc[8][4].
// Tile upsize from 128x128 (R7): counters showed latency-bound (MfmaUtil 27%,
// VALU 15%, HBM 36%, 0 conflicts) with ~2000cy/step vs ~620cy MFMA floor.
// 256^2 halves staged-bytes/MFMA (256->128B) and ds_read/MFMA (0.5->0.375),
// doubles per-barrier MFMA work per SIMD (620->1240cy) to amortize the fixed
// barrier/issue overhead. Schedule is UNCHANGED from the verified R6 ring:
//   RING-4, issue-ahead 3, single barrier per step, counted vmcnt.
//   Staging is still exactly 4 gl2lds16/thread/step (tile 2x, threads 2x),
//   so vmcnt(8)/vmcnt(4)/vmcnt(0) constants carry over verbatim.
// Safety (as R6): frags are in regs (compiler lgkm-before-MFMA) before a wave
// reaches the next barrier, so buf[(s+3)%4]=buf[(s-1)%4] is free when reused;
// vmcnt is per-wave but all waves issue symmetrically; barrier orders reuse.
// XOR swizzle chunk^=((row>>1)&3) at source: verified 0 conflicts (R4-R7).
// LDS 128KB -> 1 block/CU; all GEMM grids = 256 blocks, all co-resident.
// ---------------------------------------------------------------------------
template <int SPLITK>
__global__ __launch_bounds__(512, 2) void kan_gemm(
    const f16* __restrict__ A, const f16* __restrict__ Bt,
    float* __restrict__ C, int N, int K)
{
  __shared__ __align__(16) f16 lds[4][16384];  // ring: [buf][ A:256x32 | B:256x32 ]
  const int tid   = threadIdx.x;
  const int lane  = tid & 63;
  const int w     = tid >> 6;
  const int waveM = w >> 2, waveN = w & 3;
  const int l16   = lane & 15, quad = lane >> 4;
  const size_t mBase = (size_t)blockIdx.y * 256;
  const size_t nBase = (size_t)blockIdx.x * 256;
  const int kChunk = K / SPLITK;
  const int k0     = blockIdx.z * kChunk;
  const int kSteps = kChunk >> 5;

  // staging: A = 1024 chunks of 16B (2/thread), B same. Swizzled at source.
  const f16* gA[2]; int lA[2];
  const f16* gB[2]; int lB[2];
#pragma unroll
  for (int r = 0; r < 2; ++r) {
    int g = r * 512 + tid, row = g >> 2;
    int cs = (g & 3) ^ ((row >> 1) & 3);
    gA[r] = A + (mBase + row) * (size_t)K + k0 + cs * 8;
    gB[r] = Bt + (nBase + row) * (size_t)K + k0 + cs * 8;
    lA[r] = (r * 512 + (tid & ~63)) * 8;
    lB[r] = 8192 + lA[r];
  }

  f32x4 acc[8][4] = {};

  // preload steps 0..2 into bufs 0..2 (kSteps >= 18 in all our shapes)
#pragma unroll
  for (int p = 0; p < 3; ++p) {
    f16* b = lds[p];
    int kk = p * 32;
#pragma unroll
    for (int r = 0; r < 2; ++r) {
      gl2lds16(gA[r] + kk, b + lA[r]);
      gl2lds16(gB[r] + kk, b + lB[r]);
    }
  }

  for (int s = 0; s < kSteps; ++s) {
    // drain step-s's 4 loads only; keep later steps in flight (tail: fewer)
    if (s < kSteps - 2)       asm volatile("s_waitcnt vmcnt(8)" ::: "memory");
    else if (s == kSteps - 2) asm volatile("s_waitcnt vmcnt(4)" ::: "memory");
    else                      asm volatile("s_waitcnt vmcnt(0)" ::: "memory");
    __builtin_amdgcn_s_barrier();

    if (s + 3 < kSteps) {  // refill the buffer freed by the barrier above
      int kk = (s + 3) * 32;
      f16* b = lds[(s + 3) & 3];
#pragma unroll
      for (int r = 0; r < 2; ++r) {
        gl2lds16(gA[r] + kk, b + lA[r]);
        gl2lds16(gB[r] + kk, b + lB[r]);
      }
    }

    const f16* buf = lds[s & 3];
    f16x8 af[8], bf[4];
#pragma unroll
    for (int mi = 0; mi < 8; ++mi) {
      int row = waveM * 128 + mi * 16 + l16;
      af[mi] = *(const f16x8*)(buf + row * 32 + (quad ^ ((row >> 1) & 3)) * 8);
    }
#pragma unroll
    for (int ni = 0; ni < 4; ++ni) {
      int col = waveN * 64 + ni * 16 + l16;
      bf[ni] = *(const f16x8*)(buf + 8192 + col * 32 + (quad ^ ((col >> 1) & 3)) * 8);
    }
#pragma unroll
    for (int mi = 0; mi < 8; ++mi)
#pragma unroll
      for (int ni = 0; ni < 4; ++ni)
        acc[mi][ni] = __builtin_amdgcn_mfma_f32_16x16x32_f16(
            af[mi], bf[ni], acc[mi][ni], 0, 0, 0);
  }

#pragma unroll
  for (int mi = 0; mi < 8; ++mi) {
    size_t row = mBase + waveM * 128 + mi * 16 + quad * 4;
#pragma unroll
    for (int ni = 0; ni < 4; ++ni) {
      size_t col = nBase + waveN * 64 + ni * 16 + l16;
#pragma unroll
      for (int r = 0; r < 4; ++r)
        unsafeAtomicAdd(C + (row + r) * N + col, acc[mi][ni][r]);
    }
  }
}

// ---------------------------------------------------------------------------
// Orchestration. WS: Wt (18.9MB) | F (75.5MB) | actA | actB (16.8MB each).
// All GEMM grids = 256 blocks -> exactly 1 resident/CU (LDS 128KB cap 1),
// every block co-resident, no dispatch tail.
// ---------------------------------------------------------------------------
extern "C" void kernel_launch(void* const* d_in, const int* in_sizes, int n_in,
                              void* d_out, int out_size, void* d_ws, size_t ws_size,
                              hipStream_t stream)
{
  const float* y = (const float*)d_in[0];
  const float* u = (const float*)d_in[1];
  const float* coef[4]; const float* sb[4]; const float* ss[4];
  for (int l = 0; l < 4; ++l) {
    coef[l] = (const float*)d_in[2 + 4 * l];
    sb[l]   = (const float*)d_in[3 + 4 * l];
    ss[l]   = (const float*)d_in[4 + 4 * l];
  }
  char* ws = (char*)d_ws;
  f16*   Wt   = (f16*)(ws);
  f16*   F    = (f16*)(ws + 18874368);                        // 9216*1024*2
  float* actA = (float*)(ws + 18874368 + 75497472);           // + 4096*9216*2
  float* actB = (float*)(ws + 18874368 + 75497472 + 16777216);
  float* out  = (float*)d_out;
  const size_t actBytes = (size_t)4096 * 1024 * 4;

  // Layer 0: in=512 (concat y|u), out=1024, K=4608. splitK=4 (kSteps 36).
  kan_prep2<<<dim3(32, 16), 256, 0, stream>>>(coef[0], sb[0], ss[0], Wt, 1024, 4608);
  kan_feat<<<4096 * 256 / 256, 256, 0, stream>>>(y, F, 8, 4608, 0);
  kan_feat<<<4096 * 256 / 256, 256, 0, stream>>>(u, F, 8, 4608, 256);
  hipMemsetAsync(actA, 0, actBytes, stream);
  kan_gemm<4><<<dim3(4, 16, 4), 512, 0, stream>>>(F, Wt, actA, 1024, 4608);

  // Layer 1: in=1024, out=1024, K=9216. splitK=4 (kSteps 72).
  kan_prep2<<<dim3(32, 32), 256, 0, stream>>>(coef[1], sb[1], ss[1], Wt, 1024, 9216);
  kan_feat<<<4096 * 1024 / 256, 256, 0, stream>>>(actA, F, 10, 9216, 0);
  hipMemsetAsync(actB, 0, actBytes, stream);
  kan_gemm<4><<<dim3(4, 16, 4), 512, 0, stream>>>(F, Wt, actB, 1024, 9216);

  // Layer 2: in=1024, out=1024, K=9216. splitK=4.
  kan_prep2<<<dim3(32, 32), 256, 0, stream>>>(coef[2], sb[2], ss[2], Wt, 1024, 9216);
  kan_feat<<<4096 * 1024 / 256, 256, 0, stream>>>(actB, F, 10, 9216, 0);
  hipMemsetAsync(actA, 0, actBytes, stream);
  kan_gemm<4><<<dim3(4, 16, 4), 512, 0, stream>>>(F, Wt, actA, 1024, 9216);

  // Layer 3: in=1024, out=256, K=9216. splitK=16 -> 256 blocks (kSteps 18).
  kan_prep2<<<dim3(8, 32), 256, 0, stream>>>(coef[3], sb[3], ss[3], Wt, 256, 9216);
  kan_feat<<<4096 * 1024 / 256, 256, 0, stream>>>(actA, F, 10, 9216, 0);
  hipMemsetAsync(d_out, 0, (size_t)out_size * sizeof(float), stream);
  kan_gemm<16><<<dim3(1, 16, 16), 512, 0, stream>>>(F, Wt, out, 256, 9216);
}

// Round 2
// 635.719 us; speedup vs baseline: 1.0554x; 1.0554x over previous
//
#include <hip/hip_runtime.h>
#include <cstdint>
#include <cstddef>

typedef _Float16 f16;
typedef _Float16 f16x4 __attribute__((ext_vector_type(4)));
typedef _Float16 f16x8 __attribute__((ext_vector_type(8)));
typedef float f32x4 __attribute__((ext_vector_type(4)));

// ---------------------------------------------------------------------------
// async global->LDS, 16B per lane. LDS dest is WAVE-UNIFORM base; HW writes
// lane i at base + i*16 (m97/m104 semantics).
// ---------------------------------------------------------------------------
__device__ __forceinline__ void gl2lds16(const void* g, void* l) {
  __builtin_amdgcn_global_load_lds(
      (const __attribute__((address_space(1))) void*)(uintptr_t)g,
      (__attribute__((address_space(3))) void*)(uintptr_t)l,
      16, 0, 0);
}

// ---------------------------------------------------------------------------
// Weight prep via LDS-bounce transpose. Tile 32 o x 32 i per block.
// Wt[o][i*9+0] = sb[i,o]; Wt[o][i*9+1+g] = coef[i,o,g]*ss[i,o].
// ---------------------------------------------------------------------------
__global__ __launch_bounds__(256) void kan_prep2(
    const float* __restrict__ coef, const float* __restrict__ sb,
    const float* __restrict__ ss, f16* __restrict__ Wt,
    int out, int K9)
{
  __shared__ float s_sb[32][32];   // [i][o]
  __shared__ float s_ss[32][32];
  __shared__ f16 s_w[32][288];     // [o][i*9+t]
  const int t  = threadIdx.x;
  const int o0 = blockIdx.x * 32, i0 = blockIdx.y * 32;

  {
    int il = t >> 3, oc = (t & 7) * 4;
    float4 vb = *(const float4*)(sb + (size_t)(i0 + il) * out + o0 + oc);
    float4 vs = *(const float4*)(ss + (size_t)(i0 + il) * out + o0 + oc);
    s_sb[il][oc + 0] = vb.x; s_sb[il][oc + 1] = vb.y;
    s_sb[il][oc + 2] = vb.z; s_sb[il][oc + 3] = vb.w;
    s_ss[il][oc + 0] = vs.x; s_ss[il][oc + 1] = vs.y;
    s_ss[il][oc + 2] = vs.z; s_ss[il][oc + 3] = vs.w;
  }
  __syncthreads();

#pragma unroll
  for (int j = 0; j < 8; ++j) {
    int f  = j * 256 + t;
    int il = f >> 6, c = f & 63;
    int ol = c >> 1, gh = (c & 1) * 4;
    float4 v = *(const float4*)(coef + ((size_t)(i0 + il) * out + (o0 + ol)) * 8 + gh);
    float ssv = s_ss[il][ol];
    f16* dst = &s_w[ol][il * 9 + 1 + gh];
    dst[0] = (f16)(v.x * ssv); dst[1] = (f16)(v.y * ssv);
    dst[2] = (f16)(v.z * ssv); dst[3] = (f16)(v.w * ssv);
  }
#pragma unroll
  for (int j = 0; j < 4; ++j) {
    int e = j * 256 + t; int il = e >> 5, ol = e & 31;
    s_w[ol][il * 9] = (f16)s_sb[il][ol];
  }
  __syncthreads();

  {
    int o = t >> 3, part = t & 7;
    f16* dst = Wt + (size_t)(o0 + o) * K9 + (size_t)i0 * 9 + part * 36;
    const f16* src = &s_w[o][part * 36];
#pragma unroll
    for (int q = 0; q < 9; ++q)
      *(f16x4*)(dst + q * 4) = *(const f16x4*)(src + q * 4);
  }
}

// ---------------------------------------------------------------------------
// Features: per x -> [silu(x), B3_0(x)..B3_7(x)] fp16, row-major F[b][i*9+t].
// Uniform pykan grid hardcoded: t_j = (j-3)*0.4 - 1.
// ---------------------------------------------------------------------------
__global__ __launch_bounds__(256) void kan_feat(
    const float* __restrict__ X, f16* __restrict__ F,
    int shift, int K9, int iBase)
{
  int idx = blockIdx.x * 256 + threadIdx.x;
  int b  = idx >> shift;
  int ii = idx & ((1 << shift) - 1);
  float x = X[idx];

  float sig  = 1.0f / (1.0f + __expf(-x));
  float silu = x * sig;

  float t[12];
#pragma unroll
  for (int j = 0; j < 12; ++j) t[j] = (float)(j - 3) * 0.4f - 1.0f;
  float b0[11];
#pragma unroll
  for (int j = 0; j < 11; ++j)
    b0[j] = (x >= t[j] && x < t[j + 1]) ? 1.0f : 0.0f;
  float b1[10];
#pragma unroll
  for (int j = 0; j < 10; ++j)
    b1[j] = (x - t[j]) * 2.5f * b0[j] + (t[j + 2] - x) * 2.5f * b0[j + 1];
  float b2[9];
#pragma unroll
  for (int j = 0; j < 9; ++j)
    b2[j] = (x - t[j]) * 1.25f * b1[j] + (t[j + 3] - x) * 1.25f * b1[j + 1];
  float b3[8];
#pragma unroll
  for (int j = 0; j < 8; ++j)
    b3[j] = (x - t[j]) * (1.0f / 1.2f) * b2[j] +
            (t[j + 4] - x) * (1.0f / 1.2f) * b2[j + 1];

  f16* o = F + (size_t)b * K9 + (size_t)(iBase + ii) * 9;
  o[0] = (f16)silu;
#pragma unroll
  for (int g = 0; g < 8; ++g) o[1 + g] = (f16)b3[g];
}

// ---------------------------------------------------------------------------
// GEMM: C[M,N] += A[M,K] * Bt[N,K]^T, fp16 in / fp32 out.
// 8-PHASE SCHEDULE (m201-style port). Block 256x256, BK=64 per K-tile,
// 8 waves (2Mx4N), wave tile 128x64, acc[8][4].
// R1 post-mortem: 1 block/CU + single-barrier-per-step = one barrier domain,
// nothing fills the drain gaps (4233 cy/step vs 1240 cy MFMA floor). The
// 8-phase interleave creates intra-block overlap: per phase {ds_read subtile
// || stage 1 half-tile -> BAR -> lgkm(0) -> 16 MFMA -> BAR}, counted vmcnt
// ONLY at phases 4/8 so staging loads stay in flight across barriers.
//
// LDS: 2 bufs x [Ah0|Ah1|Bh0|Bh1] half-tile slots of 128x64 f16 = 128 KiB.
// Half-slot consumption (quadrant order (0,0),(0,1),(1,1),(1,0)):
//   A-half last read at its tile's phase 3, B-half at phase 2.
// Stage schedule/iter (t,t+1):  P1:Ah0[t+1] P2:Ah1[t+1] P3:Bh0[t+2]
//   P4:Bh1[t+2] P5:Ah0[t+2] P6:Ah1[t+2] P7:Bh0[t+3] P8:Bh1[t+3]
// vmcnt(4) at P4: leaves {Bh0,Bh1}[t+2] in flight; A/B[t+1] landed before P5.
// vmcnt(4) at P8: leaves {Bh0,Bh1}[t+3]; all of t+2 landed before next P1.
// (vmcnt(6) would leave Ah1[t+1] in flight at P5's read -> race. 4 is max.)
// Last iter: stages for tiles >= nkt skipped, vmcnt(0) at P4/P8.
//
// Swizzle: rows are 64 f16 = 8 chunks of 16B; chunk ^= (row>>1)&7 (3-bit so a
// frag read's 64 lanes cover all 8 chunk-columns evenly -> 8 dwords/bank =
// conflict-free). Inverse-swizzled at global source, LDS linear (rule #21).
// Barriers wrapped in "" memory-clobber asm so gl2lds/ds_read can't migrate
// across phase boundaries. setprio(1) around MFMA clusters (T5).
// ---------------------------------------------------------------------------
#define BARRIER() do { asm volatile("" ::: "memory"); \
    __builtin_amdgcn_s_barrier(); asm volatile("" ::: "memory"); } while (0)
#define LGKM0() asm volatile("s_waitcnt lgkmcnt(0)" ::: "memory")
#define VMC4()  asm volatile("s_waitcnt vmcnt(4)" ::: "memory")
#define VMC0()  asm volatile("s_waitcnt vmcnt(0)" ::: "memory")

#define STG_A(h, tile) do { size_t _o = (size_t)(h) * hK + (size_t)(tile) * 64; \
    f16* _d = L + ((((tile) & 1) << 15) + ((h) << 13)); \
    gl2lds16(gA[0] + _o, _d + stO0); gl2lds16(gA[1] + _o, _d + stO1); } while (0)
#define STG_B(h, tile) do { size_t _o = (size_t)(h) * hK + (size_t)(tile) * 64; \
    f16* _d = L + ((((tile) & 1) << 15) + 16384 + ((h) << 13)); \
    gl2lds16(gB[0] + _o, _d + stO0); gl2lds16(gB[1] + _o, _d + stO1); } while (0)

#define RD_ALO(pa) do { _Pragma("unroll") for (int i = 0; i < 4; ++i) { \
    a[2*i]   = *(const f16x8*)((pa) + i * 1024 + fo0); \
    a[2*i+1] = *(const f16x8*)((pa) + i * 1024 + fo1); } } while (0)
#define RD_AHI(pa) do { _Pragma("unroll") for (int i = 0; i < 4; ++i) { \
    a[2*i]   = *(const f16x8*)((pa) + 4096 + i * 1024 + fo0); \
    a[2*i+1] = *(const f16x8*)((pa) + 4096 + i * 1024 + fo1); } } while (0)
#define RD_BLO(pb) do { _Pragma("unroll") for (int i = 0; i < 2; ++i) { \
    b[2*i]   = *(const f16x8*)((pb) + i * 1024 + fo0); \
    b[2*i+1] = *(const f16x8*)((pb) + i * 1024 + fo1); } } while (0)
#define RD_BHI(pb) do { _Pragma("unroll") for (int i = 0; i < 2; ++i) { \
    b[4+2*i] = *(const f16x8*)((pb) + (2 + i) * 1024 + fo0); \
    b[5+2*i] = *(const f16x8*)((pb) + (2 + i) * 1024 + fo1); } } while (0)

#define MFMA_Q(MH, NH) do { \
  __builtin_amdgcn_s_setprio(1); \
  _Pragma("unroll") for (int kk = 0; kk < 2; ++kk) \
  _Pragma("unroll") for (int mi = 0; mi < 4; ++mi) \
  _Pragma("unroll") for (int ni = 0; ni < 2; ++ni) \
    acc[(MH)*4+mi][(NH)*2+ni] = __builtin_amdgcn_mfma_f32_16x16x32_f16( \
        a[2*mi+kk], b[2*((NH)*2+ni)+kk], acc[(MH)*4+mi][(NH)*2+ni], 0, 0, 0); \
  __builtin_amdgcn_s_setprio(0); } while (0)

template <int SPLITK>
__global__ __launch_bounds__(512, 2) void kan_gemm8(
    const f16* __restrict__ A, const f16* __restrict__ Bt,
    float* __restrict__ C, int N, int K)
{
  __shared__ __align__(16) f16 lds[65536];  // 2 x [Ah0|Ah1|Bh0|Bh1] x 8192 f16
  f16* L = lds;
  const int tid  = threadIdx.x;
  const int lane = tid & 63;
  const int w    = tid >> 6;
  const int waveM = w >> 2, waveN = w & 3;
  const int l16 = lane & 15, quad = lane >> 4;
  const size_t mBase = (size_t)blockIdx.y * 256;
  const size_t nBase = (size_t)blockIdx.x * 256;
  const int kChunk = K / SPLITK;
  const int k0  = blockIdx.z * kChunk;
  const int nkt = kChunk >> 6;            // number of 64-wide K-tiles (even)
  const size_t hK = 128 * (size_t)K;      // half-tile global row stride

  // staging: per half-tile, 1024 16B-chunks; thread covers chunks tid, 512+tid.
  // chunk c -> LDS row c>>3, pos c&7; source col-chunk = pos ^ ((row>>1)&7).
  const f16* gA[2]; const f16* gB[2];
  {
    int c0 = tid,        r0 = c0 >> 3, p0 = c0 & 7;
    int c1 = 512 + tid,  r1 = c1 >> 3, p1 = c1 & 7;
    gA[0] = A  + (mBase + r0) * (size_t)K + k0 + (p0 ^ ((r0 >> 1) & 7)) * 8;
    gA[1] = A  + (mBase + r1) * (size_t)K + k0 + (p1 ^ ((r1 >> 1) & 7)) * 8;
    gB[0] = Bt + (nBase + r0) * (size_t)K + k0 + (p0 ^ ((r0 >> 1) & 7)) * 8;
    gB[1] = Bt + (nBase + r1) * (size_t)K + k0 + (p1 ^ ((r1 >> 1) & 7)) * 8;
  }
  const int stO0 = (tid & ~63) * 8;
  const int stO1 = (512 + (tid & ~63)) * 8;

  // fragment read offsets within a half-slot (f16 units). row bits1-3 == l16
  // bits1-3, so the swizzle term is a per-thread constant.
  const int s3  = l16 >> 1;
  const int fo0 = l16 * 64 + ((quad ^ s3) & 7) * 8;        // kk=0
  const int fo1 = l16 * 64 + (((quad + 4) ^ s3) & 7) * 8;  // kk=1
  const int slotA = waveM * 8192;
  const int slotB = 16384 + (waveN >> 1) * 8192 + (waveN & 1) * 4096;

  f32x4 acc[8][4] = {};

  // prologue: tile 0 fully + B[1]; vmcnt(4) leaves {Bh0,Bh1}[1] in flight.
  STG_A(0, 0); STG_A(1, 0); STG_B(0, 0); STG_B(1, 0);
  STG_B(0, 1); STG_B(1, 1);
  VMC4();
  BARRIER();

#pragma unroll 1
  for (int it = 0; it < (nkt >> 1); ++it) {
    const int t = it * 2;
    const bool nl = (t + 2) < nkt;   // uniform; false only on last iter
    f16x8 a[8], b[8];

    { // ===== K-tile t =====
      const f16* pa = L + ((t & 1) << 15) + slotA;
      const f16* pb = L + ((t & 1) << 15) + slotB;
      // P1
      RD_ALO(pa); RD_BLO(pb);
      STG_A(0, t + 1);
      BARRIER(); LGKM0(); MFMA_Q(0, 0); BARRIER();
      // P2
      RD_BHI(pb);
      STG_A(1, t + 1);
      BARRIER(); LGKM0(); MFMA_Q(0, 1); BARRIER();
      // P3
      RD_AHI(pa);
      if (nl) STG_B(0, t + 2);
      BARRIER(); LGKM0(); MFMA_Q(1, 1); BARRIER();
      // P4
      if (nl) { STG_B(1, t + 2); VMC4(); } else { VMC0(); }
      BARRIER(); MFMA_Q(1, 0); BARRIER();
    }
    { // ===== K-tile t+1 =====
      const f16* pa = L + (((t + 1) & 1) << 15) + slotA;
      const f16* pb = L + (((t + 1) & 1) << 15) + slotB;
      // P5
      RD_ALO(pa); RD_BLO(pb);
      if (nl) STG_A(0, t + 2);
      BARRIER(); LGKM0(); MFMA_Q(0, 0); BARRIER();
      // P6
      RD_BHI(pb);
      if (nl) STG_A(1, t + 2);
      BARRIER(); LGKM0(); MFMA_Q(0, 1); BARRIER();
      // P7
      RD_AHI(pa);
      if (nl) STG_B(0, t + 3);
      BARRIER(); LGKM0(); MFMA_Q(1, 1); BARRIER();
      // P8
      if (nl) { STG_B(1, t + 3); VMC4(); } else { VMC0(); }
      BARRIER(); MFMA_Q(1, 0); BARRIER();
    }
  }

#pragma unroll
  for (int mi = 0; mi < 8; ++mi) {
    size_t row = mBase + waveM * 128 + mi * 16 + quad * 4;
#pragma unroll
    for (int ni = 0; ni < 4; ++ni) {
      size_t col = nBase + waveN * 64 + ni * 16 + l16;
#pragma unroll
      for (int r = 0; r < 4; ++r)
        unsafeAtomicAdd(C + (row + r) * N + col, acc[mi][ni][r]);
    }
  }
}

// ---------------------------------------------------------------------------
// Orchestration. WS: Wt (18.9MB) | F (75.5MB) | actA | actB (16.8MB each).
// GEMM grids: L0-L2 = 256 blocks (1/CU, LDS-capped), L3 = 192 blocks
// (splitK=12 so nkt=12 stays even for the 2-tiles/iter loop).
// ---------------------------------------------------------------------------
extern "C" void kernel_launch(void* const* d_in, const int* in_sizes, int n_in,
                              void* d_out, int out_size, void* d_ws, size_t ws_size,
                              hipStream_t stream)
{
  const float* y = (const float*)d_in[0];
  const float* u = (const float*)d_in[1];
  const float* coef[4]; const float* sb[4]; const float* ss[4];
  for (int l = 0; l < 4; ++l) {
    coef[l] = (const float*)d_in[2 + 4 * l];
    sb[l]   = (const float*)d_in[3 + 4 * l];
    ss[l]   = (const float*)d_in[4 + 4 * l];
  }
  char* ws = (char*)d_ws;
  f16*   Wt   = (f16*)(ws);
  f16*   F    = (f16*)(ws + 18874368);                        // 9216*1024*2
  float* actA = (float*)(ws + 18874368 + 75497472);           // + 4096*9216*2
  float* actB = (float*)(ws + 18874368 + 75497472 + 16777216);
  float* out  = (float*)d_out;
  const size_t actBytes = (size_t)4096 * 1024 * 4;

  // Layer 0: in=512 (concat y|u), out=1024, K=4608. splitK=4, nkt=18.
  kan_prep2<<<dim3(32, 16), 256, 0, stream>>>(coef[0], sb[0], ss[0], Wt, 1024, 4608);
  kan_feat<<<4096 * 256 / 256, 256, 0, stream>>>(y, F, 8, 4608, 0);
  kan_feat<<<4096 * 256 / 256, 256, 0, stream>>>(u, F, 8, 4608, 256);
  hipMemsetAsync(actA, 0, actBytes, stream);
  kan_gemm8<4><<<dim3(4, 16, 4), 512, 0, stream>>>(F, Wt, actA, 1024, 4608);

  // Layer 1: in=1024, out=1024, K=9216. splitK=4, nkt=36.
  kan_prep2<<<dim3(32, 32), 256, 0, stream>>>(coef[1], sb[1], ss[1], Wt, 1024, 9216);
  kan_feat<<<4096 * 1024 / 256, 256, 0, stream>>>(actA, F, 10, 9216, 0);
  hipMemsetAsync(actB, 0, actBytes, stream);
  kan_gemm8<4><<<dim3(4, 16, 4), 512, 0, stream>>>(F, Wt, actB, 1024, 9216);

  // Layer 2: in=1024, out=1024, K=9216. splitK=4.
  kan_prep2<<<dim3(32, 32), 256, 0, stream>>>(coef[2], sb[2], ss[2], Wt, 1024, 9216);
  kan_feat<<<4096 * 1024 / 256, 256, 0, stream>>>(actB, F, 10, 9216, 0);
  hipMemsetAsync(actA, 0, actBytes, stream);
  kan_gemm8<4><<<dim3(4, 16, 4), 512, 0, stream>>>(F, Wt, actA, 1024, 9216);

  // Layer 3: in=1024, out=256, K=9216. splitK=12 -> 192 blocks, nkt=12.
  kan_prep2<<<dim3(8, 32), 256, 0, stream>>>(coef[3], sb[3], ss[3], Wt, 256, 9216);
  kan_feat<<<4096 * 1024 / 256, 256, 0, stream>>>(actA, F, 10, 9216, 0);
  hipMemsetAsync(d_out, 0, (size_t)out_size * sizeof(float), stream);
  kan_gemm8<12><<<dim3(1, 16, 12), 512, 0, stream>>>(F, Wt, out, 256, 9216);
}